// Round 2
// baseline (448.862 us; speedup 1.0000x reference)
//
#include <hip/hip_runtime.h>
#include <hip/hip_fp16.h>

// LiquidNet2: B=1024, I=128, S=512, UNFOLDS=6, out v[B,S] fp32.
//
// Params packed as f16 pairs over presynaptic i (prep kernel):
// per (i-pair p, j): uint4{ half2(A_i,A_i+1), half2(C...), half2(Wn...), half2(Wp...) }
// with A = -sigma*log2e, C = sigma*mu*log2e, Wn = W*erev, Wp = W.
// sigmoid s = 1/(1 + 2^(A*v + C)); rcp done via bit-trick + 2 Newton iters
// (main pipe) so only ONE trans op (v_exp_f32) per element.

#define B_TOT 1024
#define I_DIM 128
#define S_DIM 512
#define UNFOLDS 6
#define BT 4   // batches per block

__device__ __forceinline__ float fexp2(float x) {
#if __has_builtin(__builtin_amdgcn_exp2f)
    return __builtin_amdgcn_exp2f(x);
#else
    float r; asm("v_exp_f32 %0, %1" : "=v"(r) : "v"(x)); return r;
#endif
}

// 1/d for d in [1, ~2^60): bit-trick guess (~5% rel err) + 2 Newton -> ~6e-6 rel
__device__ __forceinline__ float rcp_nr(float d) {
    float y = __int_as_float(0x7EF311C3 - __float_as_int(d));
    y = y * fmaf(-d, y, 2.0f);
    y = y * fmaf(-d, y, 2.0f);
    return y;
}

__device__ __forceinline__ __half2 u2h(unsigned int u) {
    return __builtin_bit_cast(__half2, u);
}

// two sigmoid terms (presynaptic i-pair) accumulated into num/den
__device__ __forceinline__ void sigpair(const uint4 p, float v0, float v1,
                                        float& num, float& den) {
    __half2 A  = u2h(p.x), C = u2h(p.y), Wn = u2h(p.z), Wp = u2h(p.w);
    float t0 = fmaf(__low2float(A),  v0, __low2float(C));   // v_fma_mix candidates
    float t1 = fmaf(__high2float(A), v1, __high2float(C));
    float s0 = rcp_nr(1.0f + fexp2(t0));
    float s1 = rcp_nr(1.0f + fexp2(t1));
    num = fmaf(__low2float(Wn),  s0, num);
    den = fmaf(__low2float(Wp),  s0, den);
    num = fmaf(__high2float(Wn), s1, num);
    den = fmaf(__high2float(Wp), s1, den);
}

__global__ __launch_bounds__(256) void prep_kernel(
    const float* __restrict__ sens_mu, const float* __restrict__ sens_sigma,
    const float* __restrict__ sens_W, const float* __restrict__ sens_erev,
    const float* __restrict__ mu, const float* __restrict__ sigma,
    const float* __restrict__ W, const float* __restrict__ erev,
    uint4* __restrict__ recPP, uint4* __restrict__ sensPP)
{
    const float L2E = 1.4426950408889634f;
    int idx = blockIdx.x * 256 + threadIdx.x;
    int j = idx & (S_DIM - 1);
    int p = idx >> 9;                       // pair index
    if (idx < (S_DIM / 2) * S_DIM) {
        int i0 = 2 * p, i1 = 2 * p + 1;
        float sg0 = sigma[i0 * S_DIM + j], sg1 = sigma[i1 * S_DIM + j];
        float m0  = mu[i0 * S_DIM + j],    m1  = mu[i1 * S_DIM + j];
        float w0  = W[i0 * S_DIM + j],     w1  = W[i1 * S_DIM + j];
        float e0  = erev[i0 * S_DIM + j],  e1  = erev[i1 * S_DIM + j];
        __half2 A  = __floats2half2_rn(-sg0 * L2E, -sg1 * L2E);
        __half2 C  = __floats2half2_rn(sg0 * m0 * L2E, sg1 * m1 * L2E);
        __half2 Wn = __floats2half2_rn(w0 * e0, w1 * e1);
        __half2 Wp = __floats2half2_rn(w0, w1);
        recPP[p * S_DIM + j] = make_uint4(
            __builtin_bit_cast(unsigned int, A),  __builtin_bit_cast(unsigned int, C),
            __builtin_bit_cast(unsigned int, Wn), __builtin_bit_cast(unsigned int, Wp));
    }
    if (idx < (I_DIM / 2) * S_DIM) {
        int i0 = 2 * p, i1 = 2 * p + 1;
        float sg0 = sens_sigma[i0 * S_DIM + j], sg1 = sens_sigma[i1 * S_DIM + j];
        float m0  = sens_mu[i0 * S_DIM + j],    m1  = sens_mu[i1 * S_DIM + j];
        float w0  = sens_W[i0 * S_DIM + j],     w1  = sens_W[i1 * S_DIM + j];
        float e0  = sens_erev[i0 * S_DIM + j],  e1  = sens_erev[i1 * S_DIM + j];
        __half2 A  = __floats2half2_rn(-sg0 * L2E, -sg1 * L2E);
        __half2 C  = __floats2half2_rn(sg0 * m0 * L2E, sg1 * m1 * L2E);
        __half2 Wn = __floats2half2_rn(w0 * e0, w1 * e1);
        __half2 Wp = __floats2half2_rn(w0, w1);
        sensPP[p * S_DIM + j] = make_uint4(
            __builtin_bit_cast(unsigned int, A),  __builtin_bit_cast(unsigned int, C),
            __builtin_bit_cast(unsigned int, Wn), __builtin_bit_cast(unsigned int, Wp));
    }
}

__global__ __launch_bounds__(512, 2) void liquid_main(
    const float* __restrict__ inputs,   // [B, I]
    const float* __restrict__ hx,       // [B, S]
    const float* __restrict__ input_w,  // [I]
    const float* __restrict__ input_b,  // [I]
    const uint4* __restrict__ sensPP,   // [(I/2)*S]
    const uint4* __restrict__ recPP,    // [(S/2)*S]
    const float* __restrict__ vleak,
    const float* __restrict__ gleak,
    const float* __restrict__ cm_t,
    float* __restrict__ out)            // [B, S]
{
    const int j = threadIdx.x;          // post neuron, 0..511
    const int b0 = blockIdx.x * BT;

    __shared__ float xs[BT][I_DIM];
    __shared__ float vs[BT][S_DIM];

    {
        int b = threadIdx.x >> 7, ii = threadIdx.x & 127;
        xs[b][ii] = inputs[(b0 + b) * I_DIM + ii] * input_w[ii] + input_b[ii];
    }
    #pragma unroll
    for (int k = 0; k < BT; ++k)
        vs[k][j] = hx[(b0 + k) * S_DIM + j];
    __syncthreads();

    // ---- sensory reduction (once), 32 groups of 4 i ----
    float snum[BT], sden[BT];
    #pragma unroll
    for (int b = 0; b < BT; ++b) { snum[b] = 0.f; sden[b] = 0.f; }

    {
        const uint4* colS = sensPP + j;
        uint4 a0 = colS[0 * S_DIM], a1 = colS[1 * S_DIM];
        for (int g = 0; g < I_DIM / 4; ++g) {
            int gn = (g + 1) & (I_DIM / 4 - 1);           // wraps -> harmless reload
            uint4 n0 = colS[(2 * gn) * S_DIM];
            uint4 n1 = colS[(2 * gn + 1) * S_DIM];
            #pragma unroll
            for (int b = 0; b < BT; ++b) {
                float4 xv = *(const float4*)&xs[b][4 * g];
                sigpair(a0, xv.x, xv.y, snum[b], sden[b]);
                sigpair(a1, xv.z, xv.w, snum[b], sden[b]);
            }
            a0 = n0; a1 = n1;
        }
    }

    const float gl = gleak[j], vl = vleak[j], cmj = cm_t[j];
    const float glvl = gl * vl;
    const float cg = cmj + gl;

    // ---- unfolds: 128 groups of 4 i each ----
    const uint4* colR = recPP + j;
    for (int it = 0; it < UNFOLDS; ++it) {
        float num[BT], den[BT];
        #pragma unroll
        for (int b = 0; b < BT; ++b) { num[b] = snum[b]; den[b] = sden[b]; }

        uint4 a0 = colR[0 * S_DIM], a1 = colR[1 * S_DIM];
        for (int g = 0; g < S_DIM / 4; ++g) {
            int gn = (g + 1) & (S_DIM / 4 - 1);
            uint4 n0 = colR[(2 * gn) * S_DIM];
            uint4 n1 = colR[(2 * gn + 1) * S_DIM];
            #pragma unroll
            for (int b = 0; b < BT; ++b) {
                float4 vv = *(const float4*)&vs[b][4 * g];
                sigpair(a0, vv.x, vv.y, num[b], den[b]);
                sigpair(a1, vv.z, vv.w, num[b], den[b]);
            }
            a0 = n0; a1 = n1;
        }

        float vnew[BT];
        #pragma unroll
        for (int b = 0; b < BT; ++b) {
            float vold = vs[b][j];
            vnew[b] = (fmaf(cmj, vold, glvl) + num[b]) / (cg + den[b]);
        }
        __syncthreads();
        #pragma unroll
        for (int b = 0; b < BT; ++b) vs[b][j] = vnew[b];
        __syncthreads();
    }

    #pragma unroll
    for (int b = 0; b < BT; ++b)
        out[(b0 + b) * S_DIM + j] = vs[b][j];
}

extern "C" void kernel_launch(void* const* d_in, const int* in_sizes, int n_in,
                              void* d_out, int out_size, void* d_ws, size_t ws_size,
                              hipStream_t stream) {
    const float* inputs   = (const float*)d_in[0];
    const float* hx       = (const float*)d_in[1];
    const float* input_w  = (const float*)d_in[2];
    const float* input_b  = (const float*)d_in[3];
    const float* s_mu     = (const float*)d_in[4];
    const float* s_sigma  = (const float*)d_in[5];
    const float* s_W      = (const float*)d_in[6];
    const float* s_erev   = (const float*)d_in[7];
    const float* mu       = (const float*)d_in[8];
    const float* sigma    = (const float*)d_in[9];
    const float* W        = (const float*)d_in[10];
    const float* erev     = (const float*)d_in[11];
    const float* vleak    = (const float*)d_in[12];
    const float* gleak    = (const float*)d_in[13];
    const float* cm_t     = (const float*)d_in[14];
    float* out = (float*)d_out;

    // ws layout: recPP [(S/2)*S] uint4 = 2 MB, then sensPP [(I/2)*S] uint4 = 0.5 MB
    uint4* recPP  = (uint4*)d_ws;
    uint4* sensPP = (uint4*)((char*)d_ws + (size_t)(S_DIM / 2) * S_DIM * sizeof(uint4));

    int prep_threads = (S_DIM / 2) * S_DIM;   // 131072 covers sensory range too
    prep_kernel<<<(prep_threads + 255) / 256, 256, 0, stream>>>(
        s_mu, s_sigma, s_W, s_erev, mu, sigma, W, erev, recPP, sensPP);

    liquid_main<<<B_TOT / BT, S_DIM, 0, stream>>>(
        inputs, hx, input_w, input_b, sensPP, recPP, vleak, gleak, cm_t, out);
}

// Round 3
// 423.695 us; speedup vs baseline: 1.0594x; 1.0594x over previous
//
#include <hip/hip_runtime.h>
#include <hip/hip_bf16.h>
#include <math.h>

// LiquidNet2: B=1024, I=128, S=512, UNFOLDS=6, out v[B,S] fp32.
//
// Sigmoid via LDS lookup table: s = 1/(1+2^t) is a universal function of
// t = A*v + C  (A = -sigma*log2e, C = sigma*mu*log2e).  Params are packed at
// prep time with the table-index affine baked in:
//   A' = A*SCALE,  C' = C*SCALE + (TBL_N/2 + 0.5)
// so  f = fma(A', v, C');  idx = (u32)fmed3(f, 0, TBL_N-1);  s = tbl[idx].
// Table entry k holds s at the bin center t_c = (k - TBL_N/2)/SCALE.
// Per element: 1 fma + 1 med3 + 1 cvt + 1 lshl_add + 1 ds_read_b32 + 2 fma
// -> zero transcendentals in the hot loop.

#define B_TOT 1024
#define I_DIM 128
#define S_DIM 512
#define UNFOLDS 6
#define BT 4          // batches per block
#define TBL_N 4096
#define T_MAX 14.0f   // table covers t in [-T_MAX, T_MAX]

__global__ __launch_bounds__(256) void prep_kernel(
    const float* __restrict__ sens_mu, const float* __restrict__ sens_sigma,
    const float* __restrict__ sens_W, const float* __restrict__ sens_erev,
    const float* __restrict__ mu, const float* __restrict__ sigma,
    const float* __restrict__ W, const float* __restrict__ erev,
    float4* __restrict__ recP, float4* __restrict__ sensP)
{
    const float L2E   = 1.4426950408889634f;
    const float SCALE = (float)TBL_N / (2.0f * T_MAX);     // 146.2857
    const float OFF   = (float)(TBL_N / 2) + 0.5f;         // 2048.5 (round-to-nearest baked in)
    int idx = blockIdx.x * 256 + threadIdx.x;
    if (idx < I_DIM * S_DIM) {
        float sg = sens_sigma[idx], m = sens_mu[idx], w = sens_W[idx], er = sens_erev[idx];
        float A = -sg * L2E, C = sg * m * L2E;
        sensP[idx] = make_float4(A * SCALE, C * SCALE + OFF, w * er, w);
    }
    if (idx < S_DIM * S_DIM) {
        float sg = sigma[idx], m = mu[idx], w = W[idx], er = erev[idx];
        float A = -sg * L2E, C = sg * m * L2E;
        recP[idx] = make_float4(A * SCALE, C * SCALE + OFF, w * er, w);
    }
}

__global__ __launch_bounds__(512, 2) void liquid_main(
    const float* __restrict__ inputs,   // [B, I]
    const float* __restrict__ hx,       // [B, S]
    const float* __restrict__ input_w,  // [I]
    const float* __restrict__ input_b,  // [I]
    const float4* __restrict__ sensP,   // [I*S]
    const float4* __restrict__ recP,    // [S*S]
    const float* __restrict__ vleak,
    const float* __restrict__ gleak,
    const float* __restrict__ cm_t,
    float* __restrict__ out)            // [B, S]
{
    const int j = threadIdx.x;          // post neuron, 0..511
    const int b0 = blockIdx.x * BT;

    __shared__ float tbl[TBL_N];        // 16 KB
    __shared__ float xs[BT][I_DIM];     // 2 KB
    __shared__ float vs[BT][S_DIM];     // 8 KB

    // build sigmoid table: entry k = s(t_c), t_c = (k - TBL_N/2)/SCALE
    {
        const float INV_SCALE = (2.0f * T_MAX) / (float)TBL_N;
        for (int k = threadIdx.x; k < TBL_N; k += S_DIM) {
            float tc = ((float)k - (float)(TBL_N / 2)) * INV_SCALE;
            tbl[k] = 1.0f / (1.0f + exp2f(tc));
        }
    }

    {
        int b = threadIdx.x >> 7, ii = threadIdx.x & 127;
        xs[b][ii] = inputs[(b0 + b) * I_DIM + ii] * input_w[ii] + input_b[ii];
    }
    #pragma unroll
    for (int k = 0; k < BT; ++k)
        vs[k][j] = hx[(b0 + k) * S_DIM + j];
    __syncthreads();

    const float CLHI = (float)(TBL_N - 1);   // 4095.0f (materialized once)

    // ---- sensory reduction (once) ----
    float snum[BT], sden[BT];
    #pragma unroll
    for (int b = 0; b < BT; ++b) { snum[b] = 0.f; sden[b] = 0.f; }

    for (int i = 0; i < I_DIM; i += 4) {
        float4 p[4];
        #pragma unroll
        for (int u = 0; u < 4; ++u) p[u] = sensP[(i + u) * S_DIM + j];
        #pragma unroll
        for (int b = 0; b < BT; ++b) {
            float4 xv4 = *(const float4*)&xs[b][i];
            float xv[4] = {xv4.x, xv4.y, xv4.z, xv4.w};
            #pragma unroll
            for (int u = 0; u < 4; ++u) {
                float f = fmaf(p[u].x, xv[u], p[u].y);
                f = __builtin_amdgcn_fmed3f(f, 0.0f, CLHI);
                float s = tbl[(unsigned)f];
                snum[b] = fmaf(p[u].z, s, snum[b]);
                sden[b] = fmaf(p[u].w, s, sden[b]);
            }
        }
    }

    const float gl = gleak[j], vl = vleak[j], cmj = cm_t[j];
    const float glvl = gl * vl;
    const float cg = cmj + gl;

    // ---- unfolds ----
    for (int it = 0; it < UNFOLDS; ++it) {
        float num[BT], den[BT];
        #pragma unroll
        for (int b = 0; b < BT; ++b) { num[b] = snum[b]; den[b] = sden[b]; }

        for (int i = 0; i < S_DIM; i += 4) {
            float4 p[4];
            #pragma unroll
            for (int u = 0; u < 4; ++u) p[u] = recP[(i + u) * S_DIM + j];
            #pragma unroll
            for (int b = 0; b < BT; ++b) {
                float4 vv4 = *(const float4*)&vs[b][i];
                float vv[4] = {vv4.x, vv4.y, vv4.z, vv4.w};
                #pragma unroll
                for (int u = 0; u < 4; ++u) {
                    float f = fmaf(p[u].x, vv[u], p[u].y);
                    f = __builtin_amdgcn_fmed3f(f, 0.0f, CLHI);
                    float s = tbl[(unsigned)f];
                    num[b] = fmaf(p[u].z, s, num[b]);
                    den[b] = fmaf(p[u].w, s, den[b]);
                }
            }
        }

        float vnew[BT];
        #pragma unroll
        for (int b = 0; b < BT; ++b) {
            float vold = vs[b][j];
            vnew[b] = (fmaf(cmj, vold, glvl) + num[b]) / (cg + den[b]);
        }
        __syncthreads();
        #pragma unroll
        for (int b = 0; b < BT; ++b) vs[b][j] = vnew[b];
        __syncthreads();
    }

    #pragma unroll
    for (int b = 0; b < BT; ++b)
        out[(b0 + b) * S_DIM + j] = vs[b][j];
}

extern "C" void kernel_launch(void* const* d_in, const int* in_sizes, int n_in,
                              void* d_out, int out_size, void* d_ws, size_t ws_size,
                              hipStream_t stream) {
    const float* inputs   = (const float*)d_in[0];
    const float* hx       = (const float*)d_in[1];
    const float* input_w  = (const float*)d_in[2];
    const float* input_b  = (const float*)d_in[3];
    const float* s_mu     = (const float*)d_in[4];
    const float* s_sigma  = (const float*)d_in[5];
    const float* s_W      = (const float*)d_in[6];
    const float* s_erev   = (const float*)d_in[7];
    const float* mu       = (const float*)d_in[8];
    const float* sigma    = (const float*)d_in[9];
    const float* W        = (const float*)d_in[10];
    const float* erev     = (const float*)d_in[11];
    const float* vleak    = (const float*)d_in[12];
    const float* gleak    = (const float*)d_in[13];
    const float* cm_t     = (const float*)d_in[14];
    float* out = (float*)d_out;

    // ws layout: recP [S*S] float4 (4 MB) then sensP [I*S] float4 (1 MB)
    float4* recP  = (float4*)d_ws;
    float4* sensP = (float4*)((char*)d_ws + (size_t)S_DIM * S_DIM * sizeof(float4));

    int prep_threads = S_DIM * S_DIM;
    prep_kernel<<<(prep_threads + 255) / 256, 256, 0, stream>>>(
        s_mu, s_sigma, s_W, s_erev, mu, sigma, W, erev, recP, sensP);

    liquid_main<<<B_TOT / BT, S_DIM, 0, stream>>>(
        inputs, hx, input_w, input_b, sensP, recP, vleak, gleak, cm_t, out);
}

// Round 4
// 389.989 us; speedup vs baseline: 1.1510x; 1.0864x over previous
//
#include <hip/hip_runtime.h>
#include <hip/hip_fp16.h>
#include <math.h>

// LiquidNet2: B=1024, I=128, S=512, UNFOLDS=6, out v[B,S] fp32.
//
// Sigmoid via 8-way bank-replicated LDS table (4096 entries f32):
//   s = 1/(1+2^t),  t = A*v + C,  A=-sigma*log2e, C=sigma*mu*log2e
//   f = fma(A*SCALE, v, C*SCALE+OFF); idx = (u32)med3(f,0,4095)
//   gather at byte (idx*32 + (lane&7)*4): each 8-lane class maps to a
//   disjoint 4-bank group -> ~max-5 bank load instead of 32-way random.
// Params in grouped 48B records per (group-of-4-i, j):
//   {float2 ac[4]  (A*SCALE, C*SCALE+OFF)} + {half2 wh[4] (Wn=W*erev, Wp=W)}
// Accumulation via v_fma_mix_f32 (f16 W operand, f32 accumulate).

#define B_TOT 1024
#define I_DIM 128
#define S_DIM 512
#define UNFOLDS 6
#define BT 4
#define TBL_N 4096
#define NREP 8
#define T_MAX 14.0f

struct __align__(16) Rec {
    float2   ac[4];     // (A', C') for 4 consecutive i
    unsigned wh[4];     // half2(Wn, Wp)
};

__global__ __launch_bounds__(256) void prep_kernel(
    const float* __restrict__ sens_mu, const float* __restrict__ sens_sigma,
    const float* __restrict__ sens_W, const float* __restrict__ sens_erev,
    const float* __restrict__ mu, const float* __restrict__ sigma,
    const float* __restrict__ W, const float* __restrict__ erev,
    Rec* __restrict__ recG, Rec* __restrict__ sensG)
{
    const float L2E   = 1.4426950408889634f;
    const float SCALE = (float)TBL_N / (2.0f * T_MAX);
    const float OFF   = (float)(TBL_N / 2) + 0.5f;
    int idx = blockIdx.x * 256 + threadIdx.x;
    int j = idx & (S_DIM - 1);
    int g = idx >> 9;
    if (g < S_DIM / 4) {
        Rec r;
        #pragma unroll
        for (int u = 0; u < 4; ++u) {
            int o = (g * 4 + u) * S_DIM + j;
            float sg = sigma[o], m = mu[o], w = W[o], er = erev[o];
            r.ac[u] = make_float2(-sg * L2E * SCALE, sg * m * L2E * SCALE + OFF);
            __half2 h = __floats2half2_rn(w * er, w);
            r.wh[u] = __builtin_bit_cast(unsigned, h);
        }
        recG[g * S_DIM + j] = r;
    }
    if (g < I_DIM / 4) {
        Rec r;
        #pragma unroll
        for (int u = 0; u < 4; ++u) {
            int o = (g * 4 + u) * S_DIM + j;
            float sg = sens_sigma[o], m = sens_mu[o], w = sens_W[o], er = sens_erev[o];
            r.ac[u] = make_float2(-sg * L2E * SCALE, sg * m * L2E * SCALE + OFF);
            __half2 h = __floats2half2_rn(w * er, w);
            r.wh[u] = __builtin_bit_cast(unsigned, h);
        }
        sensG[g * S_DIM + j] = r;
    }
}

// 16-element group: 4 presynaptic i x BT batches
__device__ __forceinline__ void accum_group(
    float4 q0, float4 q1, float4 q2, const float4* vv,
    const char* tblL, float CLHI, float* num, float* den)
{
    float A[4]  = {q0.x, q0.z, q1.x, q1.z};
    float C[4]  = {q0.y, q0.w, q1.y, q1.w};
    unsigned wh[4] = {__float_as_uint(q2.x), __float_as_uint(q2.y),
                      __float_as_uint(q2.z), __float_as_uint(q2.w)};
    #pragma unroll
    for (int u = 0; u < 4; ++u) {
        #pragma unroll
        for (int b = 0; b < BT; ++b) {
            float vb = (u == 0) ? vv[b].x : (u == 1) ? vv[b].y
                     : (u == 2) ? vv[b].z : vv[b].w;
            float f = __builtin_amdgcn_fmed3f(fmaf(A[u], vb, C[u]), 0.0f, CLHI);
            unsigned k = (unsigned)f;
            float s = *(const float*)(tblL + (k << 5));   // k*NREP*4
            asm("v_fma_mix_f32 %0, %1, %2, %0 op_sel:[0,0,0] op_sel_hi:[1,0,0]"
                : "+v"(num[b]) : "v"(wh[u]), "v"(s));
            asm("v_fma_mix_f32 %0, %1, %2, %0 op_sel:[1,0,0] op_sel_hi:[1,0,0]"
                : "+v"(den[b]) : "v"(wh[u]), "v"(s));
        }
    }
}

__global__ __launch_bounds__(512) void liquid_main(
    const float* __restrict__ inputs,   // [B, I]
    const float* __restrict__ hx,       // [B, S]
    const float* __restrict__ input_w,  // [I]
    const float* __restrict__ input_b,  // [I]
    const Rec* __restrict__ sensG,      // [(I/4)*S]
    const Rec* __restrict__ recG,       // [(S/4)*S]
    const float* __restrict__ vleak,
    const float* __restrict__ gleak,
    const float* __restrict__ cm_t,
    float* __restrict__ out)            // [B, S]
{
    __shared__ __align__(16) float tbl[TBL_N * NREP];   // 128 KB
    __shared__ __align__(16) float vsm[BT][S_DIM];      // 8 KB
    __shared__ __align__(16) float xsm[BT][I_DIM];      // 2 KB

    const int j = threadIdx.x;
    const int b0 = blockIdx.x * BT;

    // table: entry k covers f in [k, k+1) -> t_center = (k - TBL_N/2)/SCALE
    {
        const float INV = (2.0f * T_MAX) / (float)TBL_N;
        for (int k = j; k < TBL_N; k += S_DIM) {
            float s = 1.0f / (1.0f + exp2f((float)(k - TBL_N / 2) * INV));
            #pragma unroll
            for (int r = 0; r < NREP; ++r) tbl[k * NREP + r] = s;
        }
    }
    {
        int b = j >> 7, ii = j & 127;
        xsm[b][ii] = inputs[(b0 + b) * I_DIM + ii] * input_w[ii] + input_b[ii];
    }
    #pragma unroll
    for (int b = 0; b < BT; ++b)
        vsm[b][j] = hx[(b0 + b) * S_DIM + j];
    __syncthreads();

    const char* tblL = (const char*)(tbl + (j & (NREP - 1)));
    const float CLHI = (float)(TBL_N - 1);

    // ---- sensory reduction (once) ----
    float snum[BT], sden[BT];
    #pragma unroll
    for (int b = 0; b < BT; ++b) { snum[b] = 0.f; sden[b] = 0.f; }
    {
        const float4* q = (const float4*)(sensG + j);
        for (int g = 0; g < I_DIM / 4; ++g) {
            float4 q0 = q[0], q1 = q[1], q2 = q[2];
            q += 3 * S_DIM;                     // next record, same j
            float4 xv[BT];
            #pragma unroll
            for (int b = 0; b < BT; ++b)
                xv[b] = *(const float4*)&xsm[b][g * 4];
            accum_group(q0, q1, q2, xv, tblL, CLHI, snum, sden);
        }
    }

    const float gl = gleak[j], vl = vleak[j], cmj = cm_t[j];
    const float glvl = gl * vl;
    const float cg = cmj + gl;

    // ---- unfolds ----
    for (int it = 0; it < UNFOLDS; ++it) {
        float num[BT], den[BT];
        #pragma unroll
        for (int b = 0; b < BT; ++b) { num[b] = snum[b]; den[b] = sden[b]; }

        const float4* q = (const float4*)(recG + j);
        for (int g = 0; g < S_DIM / 4; ++g) {
            float4 q0 = q[0], q1 = q[1], q2 = q[2];
            q += 3 * S_DIM;
            float4 vv[BT];
            #pragma unroll
            for (int b = 0; b < BT; ++b)
                vv[b] = *(const float4*)&vsm[b][g * 4];
            accum_group(q0, q1, q2, vv, tblL, CLHI, num, den);
        }

        float vnew[BT];
        #pragma unroll
        for (int b = 0; b < BT; ++b) {
            float vold = vsm[b][j];
            vnew[b] = (fmaf(cmj, vold, glvl) + num[b]) / (cg + den[b]);
        }
        __syncthreads();
        #pragma unroll
        for (int b = 0; b < BT; ++b) vsm[b][j] = vnew[b];
        __syncthreads();
    }

    #pragma unroll
    for (int b = 0; b < BT; ++b)
        out[(b0 + b) * S_DIM + j] = vsm[b][j];
}

extern "C" void kernel_launch(void* const* d_in, const int* in_sizes, int n_in,
                              void* d_out, int out_size, void* d_ws, size_t ws_size,
                              hipStream_t stream) {
    const float* inputs   = (const float*)d_in[0];
    const float* hx       = (const float*)d_in[1];
    const float* input_w  = (const float*)d_in[2];
    const float* input_b  = (const float*)d_in[3];
    const float* s_mu     = (const float*)d_in[4];
    const float* s_sigma  = (const float*)d_in[5];
    const float* s_W      = (const float*)d_in[6];
    const float* s_erev   = (const float*)d_in[7];
    const float* mu       = (const float*)d_in[8];
    const float* sigma    = (const float*)d_in[9];
    const float* W        = (const float*)d_in[10];
    const float* erev     = (const float*)d_in[11];
    const float* vleak    = (const float*)d_in[12];
    const float* gleak    = (const float*)d_in[13];
    const float* cm_t     = (const float*)d_in[14];
    float* out = (float*)d_out;

    // ws: recG (S/4)*S recs * 48B = 3.0 MB, then sensG (I/4)*S * 48B = 0.75 MB
    Rec* recG  = (Rec*)d_ws;
    Rec* sensG = (Rec*)((char*)d_ws + (size_t)(S_DIM / 4) * S_DIM * sizeof(Rec));

    int prep_threads = (S_DIM / 4) * S_DIM;   // 65536 covers sensory range too
    prep_kernel<<<(prep_threads + 255) / 256, 256, 0, stream>>>(
        s_mu, s_sigma, s_W, s_erev, mu, sigma, W, erev, recG, sensG);

    liquid_main<<<B_TOT / BT, S_DIM, 0, stream>>>(
        inputs, hx, input_w, input_b, sensG, recG, vleak, gleak, cm_t, out);
}